// Round 7
// baseline (152.836 us; speedup 1.0000x reference)
//
#include <hip/hip_runtime.h>
#include <math.h>

#if defined(__has_builtin)
#  if __has_builtin(__builtin_amdgcn_exp2f)
#    define EXP2F(x) __builtin_amdgcn_exp2f(x)
#  endif
#  if __has_builtin(__builtin_amdgcn_rcpf)
#    define RCPF(x) __builtin_amdgcn_rcpf(x)
#  endif
#endif
#ifndef EXP2F
#  define EXP2F(x) exp2f(x)
#endif
#ifndef RCPF
#  define RCPF(x) (1.0f/(x))
#endif

static constexpr int Bn = 16, QN = 512, KN = 512, Hn = 64, DV = 256, DIN = 256;
static constexpr int TQ = 8;
static constexpr float TWO_LOG2E = 2.8853900817779268f;  // 2*log2(e)
static constexpr float LOG2E     = 1.4426950408889634f;

typedef __attribute__((ext_vector_type(8))) short short8;  // 8 bf16 (4 VGPRs)
typedef __attribute__((ext_vector_type(4))) float f32x4;

__device__ __forceinline__ short f2bf(float x) {          // RNE fp32->bf16
  unsigned u = __builtin_bit_cast(unsigned, x);
  u += 0x7FFF + ((u >> 16) & 1);
  return (short)(u >> 16);
}
__device__ __forceinline__ float bf2f(short h) {
  return __builtin_bit_cast(float, ((unsigned)(unsigned short)h) << 16);
}

// One-time W pack: f32 -> bf16 hi/lo, row-major [h][k] so a B-fragment is 8
// consecutive ushorts (one dwordx4). Removes all per-block W conversion VALU.
__global__ __launch_bounds__(256) void prep_kernel(
    const float* __restrict__ Wq, const float* __restrict__ Wk,
    ushort* __restrict__ wqh, ushort* __restrict__ wql,
    ushort* __restrict__ wkh, ushort* __restrict__ wkl)
{
  int i = blockIdx.x * 256 + threadIdx.x;     // 64 blocks -> 16384
  float xq = Wq[i];
  short hq = f2bf(xq);
  wqh[i] = (ushort)hq; wql[i] = (ushort)f2bf(xq - bf2f(hq));
  float xk = Wk[i];
  short hk = f2bf(xk);
  wkh[i] = (ushort)hk; wkl[i] = (ushort)f2bf(xk - bf2f(hk));
}

// Projections via MFMA, 3-pass bf16 hi/lo (numerics identical to R4/R5 which
// passed). Occupancy fix vs R5: ONE 16x16 col-tile per wave -> 4096 waves
// (1024 blocks x 4) = 16 waves/CU (R5 had 8, latency-bound; R6's scalar-load
// variant serialized on out-of-order SMEM lgkmcnt(0) drains).
// Block = 16-row tile, wave w = h-cols w*16..+15. A-tile (16 KB) is read by
// all 4 waves -> L1-served after the first. exp2 fused into the epilogue;
// ekT goes through a wave-private LDS tile so stores are coalesced along k.
__global__ __launch_bounds__(256) void proj_mfma(
    const float* __restrict__ queries, const float* __restrict__ keys,
    const ushort* __restrict__ wqh, const ushort* __restrict__ wql,
    const ushort* __restrict__ wkh, const ushort* __restrict__ wkl,
    float* __restrict__ qe, float* __restrict__ ekT)
{
  __shared__ float tr[4][16][20];                // 5.1 KB transpose tiles
  int t = threadIdx.x;
  int lane = t & 63, wid = t >> 6;
  bool is_k = blockIdx.x >= 512;
  int trow = (blockIdx.x & 511) * 16;            // row-tile within its matrix
  const float*  X  = is_k ? keys : queries;
  const ushort* Wh = is_k ? wkh : wqh;
  const ushort* Wl = is_k ? wkl : wql;
  int mr = lane & 15, quad = lane >> 4;
  const float*  xp  = X  + (size_t)(trow + mr) * DIN + quad * 8;
  const ushort* whp = Wh + (size_t)(wid * 16 + mr) * DIN + quad * 8;
  const ushort* wlp = Wl + (size_t)(wid * 16 + mr) * DIN + quad * 8;

  f32x4 acc = (f32x4){0.f, 0.f, 0.f, 0.f};
  #pragma unroll
  for (int kc = 0; kc < 8; ++kc) {
    float4 a0 = *(const float4*)(xp + kc * 32);
    float4 a1 = *(const float4*)(xp + kc * 32 + 4);
    float av[8] = {a0.x, a0.y, a0.z, a0.w, a1.x, a1.y, a1.z, a1.w};
    short8 ah, al;
    #pragma unroll
    for (int j = 0; j < 8; ++j) {
      ah[j] = f2bf(av[j]);
      al[j] = f2bf(av[j] - bf2f(ah[j]));
    }
    short8 bh = *(const short8*)(whp + kc * 32);
    short8 bl = *(const short8*)(wlp + kc * 32);
    acc = __builtin_amdgcn_mfma_f32_16x16x32_bf16(al, bh, acc, 0, 0, 0);
    acc = __builtin_amdgcn_mfma_f32_16x16x32_bf16(ah, bl, acc, 0, 0, 0);
    acc = __builtin_amdgcn_mfma_f32_16x16x32_bf16(ah, bh, acc, 0, 0, 0);
  }
  // C/D: col = lane&15 (= h-local), row = quad*4 + reg  [verified, R4/R5 passed]
  if (!is_k) {
    #pragma unroll
    for (int reg = 0; reg < 4; ++reg) {
      int row = trow + quad * 4 + reg;
      qe[(size_t)row * Hn + wid * 16 + mr] = EXP2F(acc[reg] * TWO_LOG2E);
    }
  } else {
    #pragma unroll
    for (int reg = 0; reg < 4; ++reg)            // wave-private: no barrier
      tr[wid][mr][quad * 4 + reg] = EXP2F(acc[reg] * TWO_LOG2E);
    int b = trow >> 9, kr = trow & (KN - 1);
    #pragma unroll
    for (int hp = 0; hp < 4; ++hp) {
      int h_l = hp * 4 + quad, k_l = mr;
      ekT[((size_t)b * Hn + wid * 16 + h_l) * KN + kr + k_l] = tr[wid][h_l][k_l];
    }
  }
}

// Fused attention, 512 blocks x 512 thr; each block runs TWO rank-paired
// tasks: sorted-by-L-desc ranks i and 1023-i -> per-block work ~ L_hi + L_lo
// ~ const. This removes the 2x per-CU tail structurally (R6 showed 1024
// resident blocks make any schedule-order trick a no-op).
// Score: tanh(q+k) = 1 - 2/(Eq*Ek+1) with h-PAIRED reciprocals:
//   w_a/d_a + w_b/d_b = (w_a*d_b + w_b*d_a) / (d_a*d_b)  -> 1 rcp per 2 h
// (d <= ~5e8, product <= ~2.5e17: safe in fp32). Softmax without max-
// subtraction (|score| <= sum|wv| ~ 7). PV: float2 col-pairs x 4-way k-split.
__global__ __launch_bounds__(512) void attn_kernel(
    const float* __restrict__ qe,      // [B*512, 64]  exp2(C*q)
    const float* __restrict__ ekT,     // [B, 64, 512] exp2(C*k)
    const float* __restrict__ values,  // [B, 512, 256]
    const int*   __restrict__ valid_lens,
    const float* __restrict__ wv,      // [64]
    float* __restrict__ out)           // [B, 512, 256]
{
  __shared__ __align__(16) float qes2[Hn][TQ];   // 2 KB   [h][r]
  __shared__ __align__(16) float pt[KN][12];     // 24 KB  stride 12: 0 conflicts
  __shared__ __align__(16) float pacc[3][TQ][DV];// 24 KB  k-quarter partials
  __shared__ float wsum[8][TQ];
  __shared__ float inv_s[TQ];

  int t = threadIdx.x;
  int lane = t & 63, wave = t >> 6;

  // ---- in-kernel LPT pairing: tasks order[i], order[1023-i] ----
  int iA = blockIdx.x, iB = 1023 - blockIdx.x;
  int rankA = iA >> 6, rankB = iB >> 6;
  int bA = 0, bB = 0;
  for (int bb = 0; bb < Bn; ++bb) {              // uniform scalar work
    int Lb = valid_lens[bb];
    int r = 0;
    for (int b2 = 0; b2 < Bn; ++b2) {
      int L2 = valid_lens[b2];
      r += (L2 > Lb || (L2 == Lb && b2 < bb)) ? 1 : 0;
    }
    if (r == rankA) bA = bb;
    if (r == rankB) bB = bb;
  }
  int tb[2] = {bA, bB};
  int tq[2] = {(iA & 63) * TQ, (iB & 63) * TQ};

  float S = 0.f;                                 // sum_h wv[h]
  #pragma unroll
  for (int h = 0; h < Hn; ++h) S += wv[h];

  for (int ti = 0; ti < 2; ++ti) {
    int b = tb[ti], q0 = tq[ti];
    int L = valid_lens[b];

    qes2[t >> 3][t & 7] = qe[(size_t)(b * QN + q0 + (t & 7)) * Hn + (t >> 3)];
    __syncthreads();

    // ---- scores: thread owns k = t ----
    {
      int k = t;
      float p[TQ];
      if (k < L) {
        float sc[TQ];
        #pragma unroll
        for (int r = 0; r < TQ; ++r) sc[r] = S;
        const float* kb = ekT + (size_t)b * Hn * KN + k;
        for (int h0 = 0; h0 < Hn; h0 += 8) {
          float ekv[8];
          #pragma unroll
          for (int j = 0; j < 8; ++j)            // 8 loads in flight
            ekv[j] = kb[(size_t)(h0 + j) * KN];
          #pragma unroll
          for (int jp = 0; jp < 4; ++jp) {       // paired h: 1 rcp per 2 h
            int ha = h0 + 2 * jp;
            float wa = 2.0f * wv[ha], wb = 2.0f * wv[ha + 1];
            float eka = ekv[2 * jp], ekb = ekv[2 * jp + 1];
            float4 qa0 = *(const float4*)&qes2[ha][0];
            float4 qa1 = *(const float4*)&qes2[ha][4];
            float4 qb0 = *(const float4*)&qes2[ha + 1][0];
            float4 qb1 = *(const float4*)&qes2[ha + 1][4];
            {
              float da, db, num;
              da = qa0.x * eka + 1.0f; db = qb0.x * ekb + 1.0f;
              num = wa * db + wb * da; sc[0] -= num * RCPF(da * db);
              da = qa0.y * eka + 1.0f; db = qb0.y * ekb + 1.0f;
              num = wa * db + wb * da; sc[1] -= num * RCPF(da * db);
              da = qa0.z * eka + 1.0f; db = qb0.z * ekb + 1.0f;
              num = wa * db + wb * da; sc[2] -= num * RCPF(da * db);
              da = qa0.w * eka + 1.0f; db = qb0.w * ekb + 1.0f;
              num = wa * db + wb * da; sc[3] -= num * RCPF(da * db);
              da = qa1.x * eka + 1.0f; db = qb1.x * ekb + 1.0f;
              num = wa * db + wb * da; sc[4] -= num * RCPF(da * db);
              da = qa1.y * eka + 1.0f; db = qb1.y * ekb + 1.0f;
              num = wa * db + wb * da; sc[5] -= num * RCPF(da * db);
              da = qa1.z * eka + 1.0f; db = qb1.z * ekb + 1.0f;
              num = wa * db + wb * da; sc[6] -= num * RCPF(da * db);
              da = qa1.w * eka + 1.0f; db = qb1.w * ekb + 1.0f;
              num = wa * db + wb * da; sc[7] -= num * RCPF(da * db);
            }
          }
        }
        #pragma unroll
        for (int r = 0; r < TQ; ++r) p[r] = EXP2F(sc[r] * LOG2E);
        *(float4*)&pt[k][0] = make_float4(p[0], p[1], p[2], p[3]);
        *(float4*)&pt[k][4] = make_float4(p[4], p[5], p[6], p[7]);
      } else {
        #pragma unroll
        for (int r = 0; r < TQ; ++r) p[r] = 0.f;
      }
      #pragma unroll
      for (int r = 0; r < TQ; ++r) {             // in-register row sums
        float s = p[r];
        #pragma unroll
        for (int off = 32; off > 0; off >>= 1) s += __shfl_xor(s, off, 64);
        if (lane == r) wsum[wave][r] = s;
      }
    }
    __syncthreads();
    if (t < TQ) {
      float s = 0.f;
      #pragma unroll
      for (int w = 0; w < 8; ++w) s += wsum[w][t];
      inv_s[t] = 1.0f / s;                       // read after the pacc barrier
    }

    // ---- PV: col-pair 2cp,2cp+1 (cp = t&127), k-quarter t>>7 ----
    int cp = t & 127, kq = t >> 7;
    int c = 2 * cp;
    int k0 = (L * kq) >> 2, k1 = (L * (kq + 1)) >> 2;
    float a0[TQ], a1[TQ];
    #pragma unroll
    for (int r = 0; r < TQ; ++r) { a0[r] = 0.f; a1[r] = 0.f; }
    const float* vb = values + (size_t)b * KN * DV + c;
    #pragma unroll 2
    for (int k = k0; k < k1; ++k) {
      float2 v2 = *(const float2*)(vb + (size_t)k * DV);  // coalesced
      float4 pa = *(const float4*)&pt[k][0];              // wave broadcast
      float4 pb = *(const float4*)&pt[k][4];
      a0[0] += pa.x * v2.x; a1[0] += pa.x * v2.y;
      a0[1] += pa.y * v2.x; a1[1] += pa.y * v2.y;
      a0[2] += pa.z * v2.x; a1[2] += pa.z * v2.y;
      a0[3] += pa.w * v2.x; a1[3] += pa.w * v2.y;
      a0[4] += pb.x * v2.x; a1[4] += pb.x * v2.y;
      a0[5] += pb.y * v2.x; a1[5] += pb.y * v2.y;
      a0[6] += pb.z * v2.x; a1[6] += pb.z * v2.y;
      a0[7] += pb.w * v2.x; a1[7] += pb.w * v2.y;
    }
    if (kq) {
      #pragma unroll
      for (int r = 0; r < TQ; ++r)
        *(float2*)&pacc[kq - 1][r][c] = make_float2(a0[r], a1[r]);
    }
    __syncthreads();
    if (kq == 0) {
      float* ob = out + (size_t)(b * QN + q0) * DV + c;
      #pragma unroll
      for (int r = 0; r < TQ; ++r) {
        float s0 = a0[r], s1 = a1[r];
        #pragma unroll
        for (int q = 0; q < 3; ++q) {
          float2 pp = *(const float2*)&pacc[q][r][c];
          s0 += pp.x; s1 += pp.y;
        }
        float iv = inv_s[r];
        *(float2*)(ob + (size_t)r * DV) = make_float2(s0 * iv, s1 * iv);
      }
    }
    __syncthreads();                             // LDS safe for next task
  }
}

extern "C" void kernel_launch(void* const* d_in, const int* in_sizes, int n_in,
                              void* d_out, int out_size, void* d_ws, size_t ws_size,
                              hipStream_t stream) {
  const float* queries    = (const float*)d_in[0];
  const float* keys       = (const float*)d_in[1];
  const float* values     = (const float*)d_in[2];
  const int*   valid_lens = (const int*)d_in[3];
  const float* Wq         = (const float*)d_in[4];
  const float* Wk         = (const float*)d_in[5];
  const float* wv         = (const float*)d_in[6];
  float* out = (float*)d_out;

  char* ws = (char*)d_ws;
  float*  qe  = (float*)ws;                          // [8192][64] = 2 MB
  float*  ekT = qe + (size_t)Bn * QN * Hn;           // [B,64,512] = 2 MB
  ushort* wqh = (ushort*)(ekT + (size_t)Bn * Hn * KN);
  ushort* wql = wqh + Hn * DIN;                      // 4 x 32 KB
  ushort* wkh = wql + Hn * DIN;
  ushort* wkl = wkh + Hn * DIN;

  prep_kernel<<<64, 256, 0, stream>>>(Wq, Wk, wqh, wql, wkh, wkl);
  proj_mfma<<<1024, 256, 0, stream>>>(queries, keys, wqh, wql, wkh, wkl, qe, ekT);
  attn_kernel<<<512, 512, 0, stream>>>(qe, ekT, values, valid_lens, wv, out);
}